// Round 8
// baseline (55.760 us; speedup 1.0000x reference)
//
#include <hip/hip_runtime.h>
#include <math.h>

// MultiChannelXi: xi[b,t,k,:] = sum_{s<=t} alpha_k^(t-s) h[b,s,:] / Z_{k,t}
// alpha = clip(sigmoid(raw_alpha), 1e-6, 1-1e-6),
// Z_{k,t} = (1 - alpha^(t+1)) / (1 - alpha).
//
// 4-kernel chunked scan. Key change vs r7: blocks are (128,4) with
// threadIdx.y = k (waves are k-pure), so each thread carries ONE channel's
// state -> 8 waves/block, CHUNK=16 -> 1024 blocks -> 8 waves/SIMD (full
// occupancy) for the streaming kernels. r7 ran k3 at 1 wave/SIMD and its
// dependent load->fma->store chain left it at 4.3 TB/s.
//   k1: per-chunk weighted sums L[b,c,k,:]
//   kB: per-group sums G (GRP=16)
//   kP: per-chunk entering state P from <=15 G + <=15 L (parallel, L2-hot)
//   k3: S=P; rescan 16 rows; normalize; store (pure streaming)

namespace {

constexpr int T_LEN  = 4096;
constexpr int D_DIM  = 512;
constexpr int D4     = D_DIM / 4;      // 128 float4 lanes per row
constexpr int K_CH   = 4;
constexpr int CHUNK  = 16;
constexpr int NCHUNK = T_LEN / CHUNK;  // 256
constexpr int GRP    = 16;
constexpr int NGRP   = NCHUNK / GRP;   // 16

__device__ __forceinline__ float sigmoid_clip(float x) {
    float a = 1.0f / (1.0f + expf(-x));
    return fminf(fmaxf(a, 1e-6f), 1.0f - 1e-6f);
}

__device__ __forceinline__ void fma4(float4& d, float a, const float4& x) {
    d.x = fmaf(a, d.x, x.x);
    d.y = fmaf(a, d.y, x.y);
    d.z = fmaf(a, d.z, x.z);
    d.w = fmaf(a, d.w, x.w);
}

// k1: L[b,c,k,:] = sum_{j} alpha_k^(CHUNK-1-j) * h[b, c*CHUNK+j, :]
__global__ void __launch_bounds__(512)
ema_chunk_sums(const float4* __restrict__ h4,
               const float*  __restrict__ raw_alpha,
               float4* __restrict__ lbuf) {
    const int c  = blockIdx.x % NCHUNK;
    const int b  = blockIdx.x / NCHUNK;
    const int d4 = threadIdx.x;
    const int k  = threadIdx.y;

    const float al = sigmoid_clip(raw_alpha[k]);

    float4 acc = make_float4(0.f, 0.f, 0.f, 0.f);
    const float4* hp = h4 + ((size_t)b * T_LEN + (size_t)c * CHUNK) * D4 + d4;
#pragma unroll
    for (int j = 0; j < CHUNK; ++j) {
        const float4 hv = hp[(size_t)j * D4];
        fma4(acc, al, hv);
    }
    lbuf[(((size_t)b * NCHUNK + c) * K_CH + k) * D4 + d4] = acc;
}

// kB: G[b,g,k,:] = Horner over the group's GRP L's with ratio alpha^CHUNK
__global__ void __launch_bounds__(512)
ema_group_sums(const float*  __restrict__ raw_alpha,
               const float4* __restrict__ lbuf,
               float4* __restrict__ gbuf) {
    const int g  = blockIdx.x % NGRP;
    const int b  = blockIdx.x / NGRP;
    const int d4 = threadIdx.x;
    const int k  = threadIdx.y;

    const float a  = sigmoid_clip(raw_alpha[k]);
    const float aC = exp2f((float)CHUNK * log2f(a));

    float4 G = make_float4(0.f, 0.f, 0.f, 0.f);
    const float4* lp = lbuf + (((size_t)b * NCHUNK + (size_t)g * GRP) * K_CH + k) * D4 + d4;
#pragma unroll
    for (int i = 0; i < GRP; ++i) {
        const float4 Lv = lp[(size_t)i * K_CH * D4];
        fma4(G, aC, Lv);
    }
    gbuf[(((size_t)b * NGRP + g) * K_CH + k) * D4 + d4] = G;
}

// kP: P[b,c,k,:] = state entering chunk c (Horner over <=15 G then <=15 L)
__global__ void __launch_bounds__(512)
ema_chunk_prefix(const float*  __restrict__ raw_alpha,
                 const float4* __restrict__ lbuf,
                 const float4* __restrict__ gbuf,
                 float4* __restrict__ pbuf) {
    const int c  = blockIdx.x % NCHUNK;
    const int b  = blockIdx.x / NCHUNK;
    const int d4 = threadIdx.x;
    const int k  = threadIdx.y;

    const float a   = sigmoid_clip(raw_alpha[k]);
    const float l2a = log2f(a);
    const float aC  = exp2f((float)CHUNK * l2a);          // alpha^CHUNK
    const float aG  = exp2f((float)(CHUNK * GRP) * l2a);  // alpha^(CHUNK*GRP)

    float4 S = make_float4(0.f, 0.f, 0.f, 0.f);

    const int g = c / GRP;
    const float4* gp = gbuf + ((size_t)b * NGRP * K_CH + k) * D4 + d4;
    for (int gq = 0; gq < g; ++gq) {
        const float4 Gv = gp[(size_t)gq * K_CH * D4];
        fma4(S, aG, Gv);
    }
    const float4* lp = lbuf + ((size_t)b * NCHUNK * K_CH + k) * D4 + d4;
    for (int cp = g * GRP; cp < c; ++cp) {
        const float4 Lv = lp[(size_t)cp * K_CH * D4];
        fma4(S, aC, Lv);
    }
    pbuf[(((size_t)b * NCHUNK + c) * K_CH + k) * D4 + d4] = S;
}

// k3: S = P[b,c,k]; rescan chunk; normalize; store. Pure streaming.
__global__ void __launch_bounds__(512)
ema_apply(const float4* __restrict__ h4,
          const float*  __restrict__ raw_alpha,
          const float4* __restrict__ pbuf,
          float4* __restrict__ out4) {
    const int c  = blockIdx.x % NCHUNK;
    const int b  = blockIdx.x / NCHUNK;
    const int d4 = threadIdx.x;
    const int k  = threadIdx.y;
    const int t0 = c * CHUNK;

    const float al = sigmoid_clip(raw_alpha[k]);
    const float om = 1.0f - al;
    float pw = exp2f((float)(t0 + 1) * log2f(al));  // alpha^(t+1) at j=0

    float4 S = pbuf[(((size_t)b * NCHUNK + c) * K_CH + k) * D4 + d4];

    const float4* hp = h4 + ((size_t)b * T_LEN + t0) * D4 + d4;
    float4* op = out4 + (((size_t)(b * T_LEN + t0) * K_CH + k)) * D4 + d4;

#pragma unroll
    for (int j = 0; j < CHUNK; ++j) {
        const float4 hv = hp[(size_t)j * D4];
        fma4(S, al, hv);
        const float invZ = om / fmaxf(1.0f - pw, 1e-30f);
        float4 o;
        o.x = S.x * invZ;
        o.y = S.y * invZ;
        o.z = S.z * invZ;
        o.w = S.w * invZ;
        op[(size_t)j * K_CH * D4] = o;
        pw *= al;
    }
}

} // namespace

extern "C" void kernel_launch(void* const* d_in, const int* in_sizes, int n_in,
                              void* d_out, int out_size, void* d_ws, size_t ws_size,
                              hipStream_t stream)
{
    const float4* h4        = (const float4*)d_in[0];
    const float*  raw_alpha = (const float*)d_in[1];
    float4* out4 = (float4*)d_out;

    const int B = in_sizes[0] / (T_LEN * D_DIM);  // 4

    float4* lbuf = (float4*)d_ws;                          // B*256*4*128 float4 = 8 MB
    float4* gbuf = lbuf + (size_t)B * NCHUNK * K_CH * D4;  // B*16*4*128  float4 = 512 KB
    float4* pbuf = gbuf + (size_t)B * NGRP   * K_CH * D4;  // B*256*4*128 float4 = 8 MB

    const dim3 blk(D4, K_CH);  // (128,4) = 512 threads, waves k-pure

    hipLaunchKernelGGL(ema_chunk_sums, dim3(B * NCHUNK), blk, 0, stream,
                       h4, raw_alpha, lbuf);
    hipLaunchKernelGGL(ema_group_sums, dim3(B * NGRP), blk, 0, stream,
                       raw_alpha, lbuf, gbuf);
    hipLaunchKernelGGL(ema_chunk_prefix, dim3(B * NCHUNK), blk, 0, stream,
                       raw_alpha, lbuf, gbuf, pbuf);
    hipLaunchKernelGGL(ema_apply, dim3(B * NCHUNK), blk, 0, stream,
                       h4, raw_alpha, pbuf, out4);
}